// Round 1
// baseline (221.154 us; speedup 1.0000x reference)
//
#include <hip/hip_runtime.h>

// Problem constants (reference: B=32, S=4096, D=256, float32)
constexpr int S_LEN = 4096;
constexpr int D_DIM = 256;

// ---------------------------------------------------------------------------
// Kernel 1: per-batch-row exclusive prefix sum of keep_mask.
// One block (512 threads) per batch row; each thread handles 8 elements.
// Outputs: pos[b*S + t] = exclusive prefix of keep over t, counts[b] = total.
// ---------------------------------------------------------------------------
__global__ void scan_kernel(const int* __restrict__ mask,
                            int* __restrict__ pos,
                            int* __restrict__ counts) {
    const int b = blockIdx.x;
    __shared__ int wsum[8];          // 512 threads = 8 waves
    const int tid = threadIdx.x;     // 0..511
    const int base = b * S_LEN + tid * 8;

    // vectorized mask load: 8 ints = 2 x int4
    int4 m0 = *reinterpret_cast<const int4*>(mask + base);
    int4 m1 = *reinterpret_cast<const int4*>(mask + base + 4);
    int vals[8] = {m0.x, m0.y, m0.z, m0.w, m1.x, m1.y, m1.z, m1.w};

    int local = 0;
#pragma unroll
    for (int i = 0; i < 8; ++i) local += vals[i];

    const int lane = tid & 63;
    const int wid  = tid >> 6;

    // wave-64 inclusive scan of per-thread totals
    int scan = local;
#pragma unroll
    for (int off = 1; off < 64; off <<= 1) {
        int n = __shfl_up(scan, off, 64);
        if (lane >= off) scan += n;
    }
    if (lane == 63) wsum[wid] = scan;
    __syncthreads();

    if (tid == 0) {
        int acc = 0;
#pragma unroll
        for (int i = 0; i < 8; ++i) { int t = wsum[i]; wsum[i] = acc; acc += t; }
        counts[b] = acc;
    }
    __syncthreads();

    // exclusive prefix for this thread's first element
    int excl = wsum[wid] + (scan - local);
#pragma unroll
    for (int i = 0; i < 8; ++i) {
        pos[base + i] = excl;
        excl += vals[i];
    }
}

// ---------------------------------------------------------------------------
// Kernel 2: scatter. One wave (64 lanes) per timestep row; each lane moves
// one float4 (64 lanes x 16 B = 1 KiB = the full D=256 row).
// Kept row t   -> out row pos[t]                  (copy of x[b,t,:])
// Dropped row  -> out row count + (t - pos[t])    (zeros)
// Every output row is written exactly once -> no memset needed.
// ---------------------------------------------------------------------------
__global__ void scatter_kernel(const float* __restrict__ x,
                               const int* __restrict__ mask,
                               const int* __restrict__ pos,
                               const int* __restrict__ counts,
                               float* __restrict__ out) {
    const int wave_in_block = threadIdx.x >> 6;      // 4 waves / 256-thread block
    const int lane = threadIdx.x & 63;
    const int row  = blockIdx.x * 4 + wave_in_block; // global timestep row id
    const int b = row >> 12;                         // row / 4096
    const int t = row & (S_LEN - 1);

    const int keep = mask[b * S_LEN + t];
    const int p    = pos[b * S_LEN + t];
    const int cnt  = counts[b];
    const int orow = keep ? p : (cnt + (t - p));

    const size_t in_off  = ((size_t)b * S_LEN + t)    * D_DIM;
    const size_t out_off = ((size_t)b * S_LEN + orow) * D_DIM;

    float4 v;
    if (keep) {
        v = reinterpret_cast<const float4*>(x + in_off)[lane];
    } else {
        v = make_float4(0.f, 0.f, 0.f, 0.f);
    }
    reinterpret_cast<float4*>(out + out_off)[lane] = v;
}

// ---------------------------------------------------------------------------
extern "C" void kernel_launch(void* const* d_in, const int* in_sizes, int n_in,
                              void* d_out, int out_size, void* d_ws, size_t ws_size,
                              hipStream_t stream) {
    const float* x    = (const float*)d_in[0];
    const int*   mask = (const int*)d_in[1];
    float*       out  = (float*)d_out;

    const int B = in_sizes[1] / S_LEN;   // 32

    int* pos    = (int*)d_ws;            // B*S ints
    int* counts = pos + (size_t)B * S_LEN;

    scan_kernel<<<B, 512, 0, stream>>>(mask, pos, counts);

    const int rows = B * S_LEN;          // one wave per row, 4 waves per block
    scatter_kernel<<<rows / 4, 256, 0, stream>>>(x, mask, pos, counts, out);
}